// Round 12
// baseline (104.959 us; speedup 1.0000x reference)
//
#include <hip/hip_runtime.h>
#include <math.h>

// ContextualLoss via MFMA bf16.
// X,T = reshape(50,16384)[10:50]; S = Xn^T Tn (K=40 padded to 64, bf16 MFMA);
// per input-column i: m=min_j S, M=max_j S, Z=sum_j exp((1-S/(m+eps))/h);
// CXmax_i = max(w(m),w(M))/Z (w monotone in S); loss = -log(max_i CXmax_i).
//
// R12 = R11 + (a) MI_T 4->2 (32 rows/wave) to drop VGPR below the 8-waves/
// SIMD bucket (evidence: VGPR=64 kernels pin at <=42% occupancy at any grid
// size; R9's VGPR=44 hit 58%); safe now because B comes from LDS, killing
// R9's global-load-amortization failure; (b) staging via
// __builtin_amdgcn_global_load_lds with the slot^(row&7) swizzle PRE-BAKED
// into tb's global layout (m173 pattern: linear LDS dest + inverse-swizzled
// source + swizzled read) -- deletes st[] regs (-16 VGPR) and staging VALU.

#define NCOL   16384
#define KDIM   40
#define KPAD   64
#define ROW0   10
#define EPSILON 1e-5f
#define COS_EPS 1e-8f
#define Q5L2E   7.2134752044448169f   // 5 * log2(e)  (1/h = 5)
#define JS      16                    // j slices
#define JSL     (NCOL / JS)           // 1024 j per slice
#define CHJ     64                    // j per staged chunk (8 KB)
#define NCH     (JSL / CHJ)           // 16 chunks per slice
#define TPC     (CHJ / 16)            // 4 16-wide j tiles per chunk
#define MI_T    2                     // 16-row M-subtiles per wave
#define RPB     (MI_T * 16 * 4)       // rows per block = 128
#define IBLK    (NCOL / RPB)          // 128 i-blocks

#if __has_builtin(__builtin_amdgcn_exp2f)
#define EXP2F(x) __builtin_amdgcn_exp2f(x)
#else
#define EXP2F(x) __expf((x) * 0.69314718055994531f)
#endif

// async global->LDS, 16B/lane, LDS dest = wave-uniform base + lane*16
#define GLL16(g, l)                                                           \
    __builtin_amdgcn_global_load_lds(                                         \
        (const __attribute__((address_space(1))) void*)(const void*)(g),      \
        (__attribute__((address_space(3))) void*)(void*)(l), 16, 0, 0)

typedef __attribute__((ext_vector_type(8))) short bf16x8;
typedef __attribute__((ext_vector_type(4))) float f32x4;

static __device__ __forceinline__ unsigned short f2bf(float f) {
    unsigned u = __float_as_uint(f);           // RNE float->bf16
    u += 0x7FFFu + ((u >> 16) & 1u);
    return (unsigned short)(u >> 16);
}

// ---------------- kernel 1: mu + column normalize + bf16 pack ----------------
// xb: linear [n][64]. tb: SWIZZLED [n][slot^(n&7)] so that a linear
// global_load_lds copy reproduces the bank-conflict-free LDS layout.
__global__ __launch_bounds__(256) void ctx_norm_kernel(
        const float* __restrict__ inp, const float* __restrict__ tgt,
        short* __restrict__ xb, short* __restrict__ tb) {
    int n = blockIdx.x * 256 + threadIdx.x;
    float t[KDIM], x[KDIM];
    float mu = 0.f;
#pragma unroll
    for (int r = 0; r < KDIM; ++r) { t[r] = tgt[(ROW0 + r) * NCOL + n]; mu += t[r]; }
    mu *= (1.0f / KDIM);
    float nt = 0.f;
#pragma unroll
    for (int r = 0; r < KDIM; ++r) { t[r] -= mu; nt = fmaf(t[r], t[r], nt); }
    float rnt = 1.0f / fmaxf(sqrtf(nt), COS_EPS);
    float nx = 0.f;
#pragma unroll
    for (int r = 0; r < KDIM; ++r) {
        x[r] = inp[(ROW0 + r) * NCOL + n] - mu;
        nx = fmaf(x[r], x[r], nx);
    }
    float rnx = 1.0f / fmaxf(sqrtf(nx), COS_EPS);

    short* to = tb + (size_t)n * KPAD;
    short* xo = xb + (size_t)n * KPAD;
    const int sw = n & 7;
#pragma unroll
    for (int q = 0; q < KDIM / 4; ++q) {        // q = 0..9: data
        ushort4 wt, wx;
        wt.x = f2bf(t[4*q+0] * rnt); wt.y = f2bf(t[4*q+1] * rnt);
        wt.z = f2bf(t[4*q+2] * rnt); wt.w = f2bf(t[4*q+3] * rnt);
        wx.x = f2bf(x[4*q+0] * rnx); wx.y = f2bf(x[4*q+1] * rnx);
        wx.z = f2bf(x[4*q+2] * rnx); wx.w = f2bf(x[4*q+3] * rnx);
        int p_ = ((q >> 1) ^ sw);               // 16B slot swizzle
        *reinterpret_cast<ushort4*>(to + p_ * 8 + (q & 1) * 4) = wt;
        *reinterpret_cast<ushort4*>(xo + 4 * q) = wx;
    }
    ushort4 z = {0, 0, 0, 0};
#pragma unroll
    for (int q = KDIM / 4; q < KPAD / 4; ++q) { // q = 10..15: zero pad
        int p_ = ((q >> 1) ^ sw);
        *reinterpret_cast<ushort4*>(to + p_ * 8 + (q & 1) * 4) = z;
        *reinterpret_cast<ushort4*>(xo + 4 * q) = z;
    }
}

// ---------------- kernel 2: MFMA row min/max over a j slice ----------------
// grid (IBLK, JS), 256 thr = 4 waves. Wave owns 32 i-rows (2 M-subtiles).
// B double-buffered in LDS via global_load_lds (linear copy of pre-swizzled
// tb). Read swizzle: slot = g ^ (row&7). C/D: col=lane&15, row=(lane>>4)*4+r.
__global__ __launch_bounds__(256) void ctx_stats_kernel(
        const short* __restrict__ xb, const short* __restrict__ tb,
        float* __restrict__ pmin, float* __restrict__ pmax) {
    const int tid = threadIdx.x;
    const int wave = tid >> 6, l = tid & 63;
    const int la = l & 15, g = l >> 4;
    const int ibase = blockIdx.x * RPB + wave * (MI_T * 16);
    const int js = blockIdx.y;

    __shared__ __align__(16) short ldsb[2][CHJ * KPAD];   // 2 x 8 KB

    bf16x8 a[MI_T][2];
#pragma unroll
    for (int mi = 0; mi < MI_T; ++mi)
#pragma unroll
        for (int ks = 0; ks < 2; ++ks)
            a[mi][ks] = *reinterpret_cast<const bf16x8*>(
                xb + (size_t)(ibase + mi * 16 + la) * KPAD + ks * 32 + g * 8);

    float vmn[MI_T][4], vmx[MI_T][4];
#pragma unroll
    for (int mi = 0; mi < MI_T; ++mi)
#pragma unroll
        for (int r = 0; r < 4; ++r) { vmn[mi][r] = 3.4e38f; vmx[mi][r] = -3.4e38f; }

    const short* tbase = tb + (size_t)js * JSL * KPAD;

    {   // prologue: stage chunk 0 into buffer 0 (2 x 16B per thread)
        const short* gs = tbase + tid * 8;
        short* ls = &ldsb[0][wave * 512];
        GLL16(gs, ls); GLL16(gs + 2048, ls + 2048);
    }
    __syncthreads();

    const f32x4 zero4 = {0.f, 0.f, 0.f, 0.f};
    int cb = 0;
    for (int ch = 0; ch < NCH; ++ch) {
        if (ch + 1 < NCH) {               // issue next-chunk DMA early
            const short* gs = tbase + (size_t)(ch + 1) * CHJ * KPAD + tid * 8;
            short* ls = &ldsb[cb ^ 1][wave * 512];
            GLL16(gs, ls); GLL16(gs + 2048, ls + 2048);
        }
#pragma unroll 2
        for (int jj = 0; jj < TPC; ++jj) {
            const int lr = jj * 16 + la;
            const short* lp = &ldsb[cb][lr * 64];
            bf16x8 b0 = *reinterpret_cast<const bf16x8*>(lp + ((g    ) ^ (lr & 7)) * 8);
            bf16x8 b1 = *reinterpret_cast<const bf16x8*>(lp + ((g + 4) ^ (lr & 7)) * 8);
#pragma unroll
            for (int mi = 0; mi < MI_T; ++mi) {
                f32x4 acc = __builtin_amdgcn_mfma_f32_16x16x32_bf16(a[mi][0], b0, zero4, 0, 0, 0);
                acc = __builtin_amdgcn_mfma_f32_16x16x32_bf16(a[mi][1], b1, acc, 0, 0, 0);
#pragma unroll
                for (int r = 0; r < 4; ++r) {
                    vmn[mi][r] = fminf(vmn[mi][r], acc[r]);
                    vmx[mi][r] = fmaxf(vmx[mi][r], acc[r]);
                }
            }
        }
        __syncthreads();                  // drains DMA (vmcnt) + sync readers
        cb ^= 1;
    }

    // reduce over the 16 column-lanes of each 16-lane group
#pragma unroll
    for (int off = 1; off < 16; off <<= 1)
#pragma unroll
        for (int mi = 0; mi < MI_T; ++mi)
#pragma unroll
            for (int r = 0; r < 4; ++r) {
                vmn[mi][r] = fminf(vmn[mi][r], __shfl_xor(vmn[mi][r], off, 64));
                vmx[mi][r] = fmaxf(vmx[mi][r], __shfl_xor(vmx[mi][r], off, 64));
            }
    if (la == 0) {
#pragma unroll
        for (int mi = 0; mi < MI_T; ++mi)
#pragma unroll
            for (int r = 0; r < 4; ++r) {
                int row = ibase + mi * 16 + g * 4 + r;
                pmin[js * NCOL + row] = vmn[mi][r];
                pmax[js * NCOL + row] = vmx[mi][r];
            }
    }
}

// ---------------- kernel 3: fold JS partials -> final row min/max ----------------
__global__ __launch_bounds__(256) void ctx_fold_kernel(
        const float* __restrict__ pmin, const float* __restrict__ pmax,
        float* __restrict__ rmin, float* __restrict__ rmax) {
    int i = blockIdx.x * 256 + threadIdx.x;
    float m = pmin[i], M = pmax[i];
#pragma unroll
    for (int s = 1; s < JS; ++s) {
        m = fminf(m, pmin[s * NCOL + i]);
        M = fmaxf(M, pmax[s * NCOL + i]);
    }
    rmin[i] = m; rmax[i] = M;
}

// ---------------- kernel 4: MFMA row sum of exp over a j slice ----------------
// w = exp((1-S*c)/h) = exp2(fma(S, -Q5L2E*c, Q5L2E)), c = 1/(m+eps) per row.
__global__ __launch_bounds__(256) void ctx_sumexp_kernel(
        const short* __restrict__ xb, const short* __restrict__ tb,
        const float* __restrict__ rmin, float* __restrict__ psum) {
    const int tid = threadIdx.x;
    const int wave = tid >> 6, l = tid & 63;
    const int la = l & 15, g = l >> 4;
    const int ibase = blockIdx.x * RPB + wave * (MI_T * 16);
    const int js = blockIdx.y;

    __shared__ __align__(16) short ldsb[2][CHJ * KPAD];   // 2 x 8 KB

    bf16x8 a[MI_T][2];
#pragma unroll
    for (int mi = 0; mi < MI_T; ++mi)
#pragma unroll
        for (int ks = 0; ks < 2; ++ks)
            a[mi][ks] = *reinterpret_cast<const bf16x8*>(
                xb + (size_t)(ibase + mi * 16 + la) * KPAD + ks * 32 + g * 8);

    float p[MI_T][4], zs[MI_T][4];
#pragma unroll
    for (int mi = 0; mi < MI_T; ++mi)
#pragma unroll
        for (int r = 0; r < 4; ++r) {
            int row = ibase + mi * 16 + g * 4 + r;
            float c = 1.0f / (rmin[row] + EPSILON);
            p[mi][r] = -Q5L2E * c;
            zs[mi][r] = 0.f;
        }

    const short* tbase = tb + (size_t)js * JSL * KPAD;

    {   // prologue: stage chunk 0 into buffer 0
        const short* gs = tbase + tid * 8;
        short* ls = &ldsb[0][wave * 512];
        GLL16(gs, ls); GLL16(gs + 2048, ls + 2048);
    }
    __syncthreads();

    const f32x4 zero4 = {0.f, 0.f, 0.f, 0.f};
    int cb = 0;
    for (int ch = 0; ch < NCH; ++ch) {
        if (ch + 1 < NCH) {               // issue next-chunk DMA early
            const short* gs = tbase + (size_t)(ch + 1) * CHJ * KPAD + tid * 8;
            short* ls = &ldsb[cb ^ 1][wave * 512];
            GLL16(gs, ls); GLL16(gs + 2048, ls + 2048);
        }
#pragma unroll 2
        for (int jj = 0; jj < TPC; ++jj) {
            const int lr = jj * 16 + la;
            const short* lp = &ldsb[cb][lr * 64];
            bf16x8 b0 = *reinterpret_cast<const bf16x8*>(lp + ((g    ) ^ (lr & 7)) * 8);
            bf16x8 b1 = *reinterpret_cast<const bf16x8*>(lp + ((g + 4) ^ (lr & 7)) * 8);
#pragma unroll
            for (int mi = 0; mi < MI_T; ++mi) {
                f32x4 acc = __builtin_amdgcn_mfma_f32_16x16x32_bf16(a[mi][0], b0, zero4, 0, 0, 0);
                acc = __builtin_amdgcn_mfma_f32_16x16x32_bf16(a[mi][1], b1, acc, 0, 0, 0);
#pragma unroll
                for (int r = 0; r < 4; ++r)
                    zs[mi][r] += EXP2F(fmaf(acc[r], p[mi][r], Q5L2E));
            }
        }
        __syncthreads();
        cb ^= 1;
    }

#pragma unroll
    for (int off = 1; off < 16; off <<= 1)
#pragma unroll
        for (int mi = 0; mi < MI_T; ++mi)
#pragma unroll
            for (int r = 0; r < 4; ++r)
                zs[mi][r] += __shfl_xor(zs[mi][r], off, 64);
    if (la == 0) {
#pragma unroll
        for (int mi = 0; mi < MI_T; ++mi)
#pragma unroll
            for (int r = 0; r < 4; ++r) {
                int row = ibase + mi * 16 + g * 4 + r;
                psum[js * NCOL + row] = zs[mi][r];
            }
    }
}

// ---------------- kernel 5: per-row CX-max, per-block max ----------------
__global__ __launch_bounds__(256) void ctx_reduce_kernel(
        const float* __restrict__ rmin, const float* __restrict__ rmax,
        const float* __restrict__ psum, float* __restrict__ blkmax) {
    int tid = threadIdx.x;
    int i = blockIdx.x * 256 + tid;
    float m = rmin[i], M = rmax[i], Z = psum[i];
#pragma unroll
    for (int s = 1; s < JS; ++s) Z += psum[s * NCOL + i];
    float c = 1.0f / (m + EPSILON);
    float w1 = EXP2F(fmaf(M, -Q5L2E * c, Q5L2E));
    float w2 = EXP2F(fmaf(m, -Q5L2E * c, Q5L2E));
    float best = fmaxf(w1, w2) / Z;   // CX strictly positive

    for (int off = 32; off > 0; off >>= 1)
        best = fmaxf(best, __shfl_down(best, off, 64));
    __shared__ float red[4];
    if ((tid & 63) == 0) red[tid >> 6] = best;
    __syncthreads();
    if (tid == 0)
        blkmax[blockIdx.x] = fmaxf(fmaxf(red[0], red[1]), fmaxf(red[2], red[3]));
}

// ---------------- kernel 6: 64 -> 1, -log ----------------
__global__ void ctx_loss_kernel(const float* __restrict__ blkmax,
                                float* __restrict__ out) {
    int tid = threadIdx.x;       // one wave of 64
    float best = blkmax[tid];
    for (int off = 32; off > 0; off >>= 1)
        best = fmaxf(best, __shfl_down(best, off, 64));
    if (tid == 0) out[0] = -logf(best);
}

extern "C" void kernel_launch(void* const* d_in, const int* in_sizes, int n_in,
                              void* d_out, int out_size, void* d_ws, size_t ws_size,
                              hipStream_t stream) {
    const float* inp = (const float*)d_in[0];
    const float* tgt = (const float*)d_in[1];
    float* out = (float*)d_out;

    // ws layout (bytes):
    //   xb     bf16 [16384][64]  2 MB   (linear)
    //   tb     bf16 [16384][64]  2 MB   (slot-swizzled layout)
    //   pmin   f32  [16][16384]  1 MB
    //   pmax   f32  [16][16384]  1 MB
    //   psum   f32  [16][16384]  1 MB
    //   rmin   f32  [16384]      64 KB
    //   rmax   f32  [16384]      64 KB
    //   blkmax f32  [64]
    char* base = (char*)d_ws;
    short* xb     = (short*)(base);
    short* tb     = (short*)(base + (size_t)2 * NCOL * KPAD);           // +2MB
    float* pmin   = (float*)(base + (size_t)4 * NCOL * KPAD);           // +4MB
    float* pmax   = pmin + (size_t)JS * NCOL;
    float* psum   = pmax + (size_t)JS * NCOL;
    float* rmin   = psum + (size_t)JS * NCOL;
    float* rmax   = rmin + NCOL;
    float* blkmax = rmax + NCOL;

    dim3 grid2(IBLK, JS);
    ctx_norm_kernel  <<<NCOL / 256, 256, 0, stream>>>(inp, tgt, xb, tb);
    ctx_stats_kernel <<<grid2, 256, 0, stream>>>(xb, tb, pmin, pmax);
    ctx_fold_kernel  <<<NCOL / 256, 256, 0, stream>>>(pmin, pmax, rmin, rmax);
    ctx_sumexp_kernel<<<grid2, 256, 0, stream>>>(xb, tb, rmin, psum);
    ctx_reduce_kernel<<<NCOL / 256, 256, 0, stream>>>(rmin, rmax, psum, blkmax);
    ctx_loss_kernel  <<<1, 64, 0, stream>>>(blkmax, out);
}